// Round 1
// 1115.392 us; speedup vs baseline: 1.0222x; 1.0222x over previous
//
#include <hip/hip_runtime.h>
#include <math.h>
#include <stdint.h>

#define N_ENT 14541
#define EMB_DIM 768
#define TOP_K 1000
#define NEG_TIMES 5
#define BS 128
#define MARGIN 0.5f
#define KCHUNKS 8
#define KPER (TOP_K / KCHUNKS)      // 125
#define EMB_BLOCKS (BS * KCHUNKS)   // 1024

// ws layout (in floats)
#define MEAN_OFF 0                                        // 14541 floats
#define PART_OFF 16384                                    // BS*KCHUNKS*2*EMB_DIM = 1,572,864 floats
#define LOSS_OFF (PART_OFF + BS * KCHUNKS * 2 * EMB_DIM)  // 128 floats

// Block-wide sum. Result valid on thread 0 only. Safe to call repeatedly
// (leading __syncthreads covers reuse of the static LDS scratch).
__device__ __forceinline__ float blockReduceSum(float v) {
    __shared__ float red[16];
    int lane = threadIdx.x & 63;
    int wid  = threadIdx.x >> 6;
#pragma unroll
    for (int o = 32; o > 0; o >>= 1) v += __shfl_down(v, o, 64);
    __syncthreads();
    if (lane == 0) red[wid] = v;
    __syncthreads();
    float s = 0.f;
    if (threadIdx.x == 0) {
        int nw = (blockDim.x + 63) >> 6;
        s = red[0];
        for (int i = 1; i < nw; ++i) s += red[i];
    }
    return s;
}

// Stage 1 (fused): blocks [0, EMB_BLOCKS) do the embedding gather partials
// (L3-bound: emb table is 44.7 MB, fits Infinity Cache); blocks
// [EMB_BLOCKS, EMB_BLOCKS+N_ENT) do simi row means (HBM-bound: 846 MB stream).
// The two phases use disjoint memory tiers, so running them concurrently
// overlaps gather latency under the HBM stream. Gather blocks are placed
// FIRST so they dispatch immediately and stay resident while row blocks
// cycle through the CUs.
__global__ void stage1_kernel(const float* __restrict__ simi,
                              float* __restrict__ mean,
                              const int* __restrict__ ent_idx,
                              const float* __restrict__ emb,
                              float* __restrict__ part) {
    if (blockIdx.x < EMB_BLOCKS) {
        // ---- embedding partial sums / sumsq ----
        int blk = blockIdx.x;
        int b = blk >> 3;       // sample
        int c = blk & 7;        // k-chunk
        int t = threadIdx.x;

        __shared__ int sidx[KPER];
        const int* idx = ent_idx + b * TOP_K + c * KPER;
        if (t < KPER) sidx[t] = idx[t];
        __syncthreads();

        float s1a = 0.f, s1b = 0.f, s1c = 0.f;
        float s2a = 0.f, s2b = 0.f, s2c = 0.f;
#pragma unroll 5
        for (int k = 0; k < KPER; ++k) {
            const float* r = emb + (size_t)sidx[k] * EMB_DIM;
            float a  = r[t];
            float bb = r[t + 256];
            float cc = r[t + 512];
            s1a += a;  s2a += a * a;
            s1b += bb; s2b += bb * bb;
            s1c += cc; s2c += cc * cc;
        }

        float* o = part + (size_t)blk * (2 * EMB_DIM);
        o[t]           = s1a; o[t + 256]           = s1b; o[t + 512]           = s1c;
        o[EMB_DIM + t] = s2a; o[EMB_DIM + 256 + t] = s2b; o[EMB_DIM + 512 + t] = s2c;
    } else {
        // ---- simi row mean (846 MB HBM stream) ----
        int row = blockIdx.x - EMB_BLOCKS;
        const float* p = simi + (size_t)row * N_ENT;
        float s = 0.f;

        uintptr_t addr = (uintptr_t)p;
        int head = (int)(((16u - (addr & 15u)) & 15u) >> 2);  // floats to 16B align
        if (head > N_ENT) head = N_ENT;
        if ((int)threadIdx.x < head) s += p[threadIdx.x];

        int n = N_ENT - head;
        const float4* p4 = (const float4*)(p + head);
        int n4 = n >> 2;
        for (int i = threadIdx.x; i < n4; i += 256) {
            float4 v = p4[i];
            s += (v.x + v.y) + (v.z + v.w);
        }
        int tail = n & 3;
        if ((int)threadIdx.x < tail) s += p[head + (n4 << 2) + threadIdx.x];

        s = blockReduceSum(s);
        if (threadIdx.x == 0) mean[row] = s * (1.0f / N_ENT);
    }
}

// Stage 2: per-sample finalize — std, fused feature@w dot, sigmoid, hinge partial.
__global__ void finalize_kernel(const float* __restrict__ mean,
                                const float* __restrict__ part,
                                const int* __restrict__ ent_idx,
                                const float* __restrict__ stelp,
                                const float* __restrict__ rotate,
                                const float* __restrict__ w,
                                const float* __restrict__ bbias,
                                const float* __restrict__ pos_s,
                                const float* __restrict__ pos_r,
                                const float* __restrict__ neg_s,
                                const float* __restrict__ neg_r,
                                float* __restrict__ loss_part) {
    int b = blockIdx.x;
    int t = threadIdx.x;
    float acc = 0.f;

    const float* pb = part + (size_t)b * KCHUNKS * 2 * EMB_DIM;
#pragma unroll
    for (int j = 0; j < 3; ++j) {
        int d = t + j * 256;
        float s1 = 0.f, s2 = 0.f;
#pragma unroll
        for (int c = 0; c < KCHUNKS; ++c) {
            s1 += pb[c * (2 * EMB_DIM) + d];
            s2 += pb[c * (2 * EMB_DIM) + EMB_DIM + d];
        }
        float var = (s2 - s1 * s1 * (1.0f / TOP_K)) * (1.0f / (TOP_K - 1));
        var = fmaxf(var, 0.f);
        acc += sqrtf(var) * w[d];
    }

    for (int k = t; k < TOP_K; k += 256) {
        int e = ent_idx[b * TOP_K + k];
        float sm = mean[e];
        float s = stelp[b * TOP_K + k];
        float r = rotate[b * TOP_K + k];
        acc += sm * w[EMB_DIM + k]
             + fabsf(r - s) * w[EMB_DIM + TOP_K + k]
             + (s + r) * w[EMB_DIM + 2 * TOP_K + k]
             + s * w[EMB_DIM + 3 * TOP_K + k]
             + r * w[EMB_DIM + 4 * TOP_K + k];
    }

    float logit = blockReduceSum(acc);
    if (t == 0) {
        logit += bbias[0];
        float alpha = 1.0f / (1.0f + expf(-logit));
        float pe = alpha * pos_s[b] + (1.0f - alpha) * pos_r[b];
        float l = 0.f;
#pragma unroll
        for (int j = 0; j < NEG_TIMES; ++j) {
            float ne = alpha * neg_s[b * NEG_TIMES + j] +
                       (1.0f - alpha) * neg_r[b * NEG_TIMES + j];
            l += fmaxf(0.f, MARGIN - pe + ne);
        }
        loss_part[b] = l;
    }
}

// Stage 3: final scalar reduce.
__global__ void reduce_loss_kernel(const float* __restrict__ loss_part,
                                   float* __restrict__ out) {
    float v = ((int)threadIdx.x < BS) ? loss_part[threadIdx.x] : 0.f;
    v = blockReduceSum(v);
    if (threadIdx.x == 0) out[0] = v * (1.0f / (BS * NEG_TIMES));
}

extern "C" void kernel_launch(void* const* d_in, const int* in_sizes, int n_in,
                              void* d_out, int out_size, void* d_ws, size_t ws_size,
                              hipStream_t stream) {
    const float* pos_s  = (const float*)d_in[0];
    const float* pos_r  = (const float*)d_in[1];
    const int*   ent_i  = (const int*)d_in[2];
    const float* neg_s  = (const float*)d_in[3];
    const float* neg_r  = (const float*)d_in[4];
    const float* stelp  = (const float*)d_in[5];
    const float* rotate = (const float*)d_in[6];
    const float* emb    = (const float*)d_in[7];
    const float* simi   = (const float*)d_in[8];
    const float* w      = (const float*)d_in[9];
    const float* bb     = (const float*)d_in[10];

    float* ws    = (float*)d_ws;
    float* mean  = ws + MEAN_OFF;
    float* part  = ws + PART_OFF;
    float* lossp = ws + LOSS_OFF;
    float* out   = (float*)d_out;

    hipLaunchKernelGGL(stage1_kernel, dim3(EMB_BLOCKS + N_ENT), dim3(256), 0, stream,
                       simi, mean, ent_i, emb, part);
    hipLaunchKernelGGL(finalize_kernel, dim3(BS), dim3(256), 0, stream,
                       mean, part, ent_i, stelp, rotate, w, bb,
                       pos_s, pos_r, neg_s, neg_r, lossp);
    hipLaunchKernelGGL(reduce_loss_kernel, dim3(1), dim3(128), 0, stream, lossp, out);
}